// Round 4
// baseline (1332.280 us; speedup 1.0000x reference)
//
#include <hip/hip_runtime.h>

#define T_STEPS 1024
#define NZV 60          // valid z width
#define H 128
#define NY 8
#define NU 4
#define ZSTR 72         // padded LDS stride (shorts) for z
#define HSTR 136        // padded LDS stride (shorts) for h1/h2

typedef __attribute__((ext_vector_type(8))) short bf16x8;
typedef __attribute__((ext_vector_type(4))) short bf16x4;
typedef __attribute__((ext_vector_type(4))) float f32x4;

__device__ __forceinline__ unsigned short f2bf(float x) {
    unsigned u = __float_as_uint(x);
    u += 0x7FFFu + ((u >> 16) & 1u);
    return (unsigned short)(u >> 16);
}

// tanh(x) = 1 - 2/(exp(2x)+1); exp2 saturates to inf/0 so no clamp needed.
__device__ __forceinline__ float tanh_fast(float x) {
    float e = __builtin_amdgcn_exp2f(x * 2.8853900817779268f);
    return fmaf(-2.0f, __builtin_amdgcn_rcpf(e + 1.0f), 1.0f);
}

__global__ __launch_bounds__(256, 2)
void cstr_scan_kernel(const float* __restrict__ u_g, const float* __restrict__ z0_g,
                      const float* __restrict__ W1, const float* __restrict__ b1,
                      const float* __restrict__ W2, const float* __restrict__ b2,
                      const float* __restrict__ W3, const float* __restrict__ b3,
                      float* __restrict__ out) {
    __shared__ unsigned short zbuf[2][16][ZSTR];
    __shared__ unsigned short h1s[16][HSTR];
    __shared__ unsigned short h2s[2][16][HSTR];

    const int tid   = threadIdx.x;
    const int wid   = tid >> 6;          // 0..3
    const int lane  = tid & 63;
    const int b0    = blockIdx.x * 16;   // batch row base
    const int col   = lane & 15;         // MFMA col / A row
    const int kg    = lane >> 4;         // 0..3 (k-group)
    const int wrow0 = kg * 4;            // C-frag row base
    const int urow  = lane >> 2;         // u/z-shift row
    const int uc    = lane & 3;
    const int nbase = wid * 32;          // this wave's hidden-col base (2 n-tiles)

    // ---- preload weight fragments ----
    // w1f: W1 with rows [32,40) (the y-slot) AND rows >=60 zeroed.
    // w1yx: ONLY rows [32,40) of W1 (K-window 32..63) — used once at t==0.
    // w4f: W4 = W3 @ W1[32:40,:]  (rank-8 composition; y's path into GEMM1).
    bf16x8 w1f[2][2], w1yx[2], w4f[4][2], w2f[4][2], w3f[4];
    float b1v[2], b1e[2], b2v[2], b3v;
#pragma unroll
    for (int nl = 0; nl < 2; ++nl) {
        const int n = nbase + nl * 16 + col;
        b1v[nl] = b1[n];
        float corr = 0.f;
#pragma unroll
        for (int m = 0; m < NY; ++m) corr += b3[m] * W1[(32 + m) * H + n];
        b1e[nl] = b1v[nl] + corr;
        b2v[nl] = b2[n];
    }
    b3v = (col < NY) ? b3[col] : 0.f;

#pragma unroll
    for (int kc = 0; kc < 2; ++kc)
#pragma unroll
        for (int nl = 0; nl < 2; ++nl) {
            const int n = nbase + nl * 16 + col;
            bf16x8 v;
#pragma unroll
            for (int j = 0; j < 8; ++j) {
                int k = kc * 32 + kg * 8 + j;
                float w = (k < NZV && !(k >= 32 && k < 40)) ? W1[k * H + n] : 0.f;
                v[j] = (short)f2bf(w);
            }
            w1f[kc][nl] = v;
        }
#pragma unroll
    for (int nl = 0; nl < 2; ++nl) {
        const int n = nbase + nl * 16 + col;
        bf16x8 v;
#pragma unroll
        for (int j = 0; j < 8; ++j) {
            int k = 32 + kg * 8 + j;
            float w = (k < 40) ? W1[k * H + n] : 0.f;
            v[j] = (short)f2bf(w);
        }
        w1yx[nl] = v;
    }
#pragma unroll
    for (int kc = 0; kc < 4; ++kc)
#pragma unroll
        for (int nl = 0; nl < 2; ++nl) {
            const int n = nbase + nl * 16 + col;
            bf16x8 v;
#pragma unroll
            for (int j = 0; j < 8; ++j) {
                int k = kc * 32 + kg * 8 + j;
                float acc = 0.f;
#pragma unroll
                for (int m = 0; m < NY; ++m)
                    acc += W3[k * NY + m] * W1[(32 + m) * H + n];
                v[j] = (short)f2bf(acc);
            }
            w4f[kc][nl] = v;
        }
#pragma unroll
    for (int kc = 0; kc < 4; ++kc)
#pragma unroll
        for (int nl = 0; nl < 2; ++nl) {
            const int n = nbase + nl * 16 + col;
            bf16x8 v;
#pragma unroll
            for (int j = 0; j < 8; ++j)
                v[j] = (short)f2bf(W2[(kc * 32 + kg * 8 + j) * H + n]);
            w2f[kc][nl] = v;
        }
#pragma unroll
    for (int kc = 0; kc < 4; ++kc) {
        bf16x8 v;
#pragma unroll
        for (int j = 0; j < 8; ++j) {
            int k = kc * 32 + kg * 8 + j;
            float w = (col < NY) ? W3[k * NY + col] : 0.f;
            v[j] = (short)f2bf(w);
        }
        w3f[kc] = v;
    }

    // ---- init LDS: z buffers + h2prev(=0 for t=0) ----
    {
        unsigned short* zs = &zbuf[0][0][0];
        for (int i = tid; i < 2 * 16 * ZSTR; i += 256) zs[i] = 0;
        unsigned short* hs = &h2s[0][0][0];
        for (int i = tid; i < 2 * 16 * HSTR; i += 256) hs[i] = 0;
        __syncthreads();
        for (int i = tid; i < 16 * NZV; i += 256) {
            int r = i / NZV, c = i - r * NZV;
            zbuf[0][r][c] = f2bf(z0_g[(size_t)(b0 + r) * NZV + c]);
        }
        __syncthreads();
    }

    float ureg = 0.f, ureg_n = 0.f;
    if (wid == 3)
        ureg = u_g[(size_t)(b0 + urow) * (T_STEPS * NU) + uc];

    int cur = 0, ph = 0;
#pragma unroll 1
    for (int t = 0; t < T_STEPS; ++t) {
        const int nxt = cur ^ 1;

        if (wid == 3 && t + 1 < T_STEPS)
            ureg_n = u_g[(size_t)(b0 + urow) * (T_STEPS * NU) + (size_t)(t + 1) * NU + uc];

        // ---- phase A: GEMM1' = z@W1(y-rows zeroed) + h2prev@W4  (+ t0 fix) ----
        bf16x8 za0 = *(const bf16x8*)&zbuf[cur][col][kg * 8];
        bf16x8 za1 = *(const bf16x8*)&zbuf[cur][col][32 + kg * 8];
        bf16x8 hp0 = *(const bf16x8*)&h2s[ph][col][0 * 32 + kg * 8];
        bf16x8 hp1 = *(const bf16x8*)&h2s[ph][col][1 * 32 + kg * 8];
        bf16x8 hp2 = *(const bf16x8*)&h2s[ph][col][2 * 32 + kg * 8];
        bf16x8 hp3 = *(const bf16x8*)&h2s[ph][col][3 * 32 + kg * 8];
#pragma unroll
        for (int nl = 0; nl < 2; ++nl) {
            float seed = t ? b1e[nl] : b1v[nl];
            f32x4 s0 = { seed, seed, seed, seed };
            f32x4 s1 = { 0.f, 0.f, 0.f, 0.f };
            s0 = __builtin_amdgcn_mfma_f32_16x16x32_bf16(za0, w1f[0][nl], s0, 0, 0, 0);
            s1 = __builtin_amdgcn_mfma_f32_16x16x32_bf16(hp0, w4f[0][nl], s1, 0, 0, 0);
            s0 = __builtin_amdgcn_mfma_f32_16x16x32_bf16(za1, w1f[1][nl], s0, 0, 0, 0);
            s1 = __builtin_amdgcn_mfma_f32_16x16x32_bf16(hp1, w4f[1][nl], s1, 0, 0, 0);
            s0 = __builtin_amdgcn_mfma_f32_16x16x32_bf16(hp2, w4f[2][nl], s0, 0, 0, 0);
            s1 = __builtin_amdgcn_mfma_f32_16x16x32_bf16(hp3, w4f[3][nl], s1, 0, 0, 0);
            if (t == 0)
                s0 = __builtin_amdgcn_mfma_f32_16x16x32_bf16(za1, w1yx[nl], s0, 0, 0, 0);
            f32x4 c1 = s0 + s1;
#pragma unroll
            for (int r = 0; r < 4; ++r)
                h1s[wrow0 + r][nbase + nl * 16 + col] = f2bf(tanh_fast(c1[r]));
        }
        // wave0 (overlapped): y_{t-1} = h2prev@W3 + b3; insert into z[cur] + store
        if (wid == 0 && t > 0) {
            f32x4 ya = { b3v, b3v, b3v, b3v };
            f32x4 yb = { 0.f, 0.f, 0.f, 0.f };
            ya = __builtin_amdgcn_mfma_f32_16x16x32_bf16(hp0, w3f[0], ya, 0, 0, 0);
            yb = __builtin_amdgcn_mfma_f32_16x16x32_bf16(hp1, w3f[1], yb, 0, 0, 0);
            ya = __builtin_amdgcn_mfma_f32_16x16x32_bf16(hp2, w3f[2], ya, 0, 0, 0);
            yb = __builtin_amdgcn_mfma_f32_16x16x32_bf16(hp3, w3f[3], yb, 0, 0, 0);
            f32x4 y = ya + yb;
            if (col < NY) {
#pragma unroll
                for (int r = 0; r < 4; ++r)
                    zbuf[cur][wrow0 + r][32 + col] = f2bf(y[r]);
#pragma unroll
                for (int r = 0; r < 4; ++r)
                    out[(size_t)(b0 + wrow0 + r) * (T_STEPS * NY) + (size_t)(t - 1) * NY + col] = y[r];
            }
        }
        __syncthreads();   // B1: h1 ready; y_{t-1} in z[cur]

        // ---- phase B: GEMM2 (h1 @ W2) ; wave3 overlaps z-shift ----
        bf16x8 ha0 = *(const bf16x8*)&h1s[col][0 * 32 + kg * 8];
        bf16x8 ha1 = *(const bf16x8*)&h1s[col][1 * 32 + kg * 8];
        bf16x8 ha2 = *(const bf16x8*)&h1s[col][2 * 32 + kg * 8];
        bf16x8 ha3 = *(const bf16x8*)&h1s[col][3 * 32 + kg * 8];
#pragma unroll
        for (int nl = 0; nl < 2; ++nl) {
            f32x4 a0 = { b2v[nl], b2v[nl], b2v[nl], b2v[nl] };
            f32x4 a1 = { 0.f, 0.f, 0.f, 0.f };
            a0 = __builtin_amdgcn_mfma_f32_16x16x32_bf16(ha0, w2f[0][nl], a0, 0, 0, 0);
            a1 = __builtin_amdgcn_mfma_f32_16x16x32_bf16(ha1, w2f[1][nl], a1, 0, 0, 0);
            a0 = __builtin_amdgcn_mfma_f32_16x16x32_bf16(ha2, w2f[2][nl], a0, 0, 0, 0);
            a1 = __builtin_amdgcn_mfma_f32_16x16x32_bf16(ha3, w2f[3][nl], a1, 0, 0, 0);
            f32x4 c2 = a0 + a1;
#pragma unroll
            for (int r = 0; r < 4; ++r)
                h2s[ph ^ 1][wrow0 + r][nbase + nl * 16 + col] = f2bf(tanh_fast(c2[r]));
        }
        // wave3 (overlapped): z shift cur->nxt + u insert (y slot 32..39 untouched)
        if (wid == 3) {
            bf16x4 m0 = *(const bf16x4*)&zbuf[cur][urow][8 + 8 * uc];
            bf16x4 m1 = *(const bf16x4*)&zbuf[cur][urow][12 + 8 * uc];
            bf16x4 m2 = *(const bf16x4*)&zbuf[cur][urow][44 + 4 * uc];
            *(bf16x4*)&zbuf[nxt][urow][8 * uc]      = m0;
            *(bf16x4*)&zbuf[nxt][urow][8 * uc + 4]  = m1;
            *(bf16x4*)&zbuf[nxt][urow][40 + 4 * uc] = m2;
            zbuf[nxt][urow][56 + uc] = f2bf(ureg);
        }
        __syncthreads();   // B2: h2 ready; z[nxt] ready (minus y-slot)

        cur = nxt;
        ph ^= 1;
        ureg = ureg_n;
    }

    // ---- epilogue: y_{T-1} from final h2 ----
    if (wid == 0) {
        bf16x8 hp0 = *(const bf16x8*)&h2s[ph][col][0 * 32 + kg * 8];
        bf16x8 hp1 = *(const bf16x8*)&h2s[ph][col][1 * 32 + kg * 8];
        bf16x8 hp2 = *(const bf16x8*)&h2s[ph][col][2 * 32 + kg * 8];
        bf16x8 hp3 = *(const bf16x8*)&h2s[ph][col][3 * 32 + kg * 8];
        f32x4 ya = { b3v, b3v, b3v, b3v };
        f32x4 yb = { 0.f, 0.f, 0.f, 0.f };
        ya = __builtin_amdgcn_mfma_f32_16x16x32_bf16(hp0, w3f[0], ya, 0, 0, 0);
        yb = __builtin_amdgcn_mfma_f32_16x16x32_bf16(hp1, w3f[1], yb, 0, 0, 0);
        ya = __builtin_amdgcn_mfma_f32_16x16x32_bf16(hp2, w3f[2], ya, 0, 0, 0);
        yb = __builtin_amdgcn_mfma_f32_16x16x32_bf16(hp3, w3f[3], yb, 0, 0, 0);
        f32x4 y = ya + yb;
        if (col < NY) {
#pragma unroll
            for (int r = 0; r < 4; ++r)
                out[(size_t)(b0 + wrow0 + r) * (T_STEPS * NY) + (size_t)(T_STEPS - 1) * NY + col] = y[r];
        }
    }
}

extern "C" void kernel_launch(void* const* d_in, const int* in_sizes, int n_in,
                              void* d_out, int out_size, void* d_ws, size_t ws_size,
                              hipStream_t stream) {
    (void)in_sizes; (void)n_in; (void)d_ws; (void)ws_size; (void)out_size;
    const float* u  = (const float*)d_in[0];
    const float* z0 = (const float*)d_in[1];
    const float* W1 = (const float*)d_in[2];
    const float* b1 = (const float*)d_in[3];
    const float* W2 = (const float*)d_in[4];
    const float* b2 = (const float*)d_in[5];
    const float* W3 = (const float*)d_in[6];
    const float* b3 = (const float*)d_in[7];
    float* out = (float*)d_out;

    dim3 grid(8192 / 16);   // 512 blocks x 4 waves; 16 batch rows/block
    dim3 block(256);
    cstr_scan_kernel<<<grid, block, 0, stream>>>(u, z0, W1, b1, W2, b2, W3, b3, out);
}

// Round 5
// 1082.777 us; speedup vs baseline: 1.2304x; 1.2304x over previous
//
#include <hip/hip_runtime.h>

#define T_STEPS 1024
#define NZV 60          // valid z width
#define H 128
#define NY 8
#define NU 4
#define ZSTR 72         // padded LDS stride (shorts) for z
#define HSTR 136        // padded LDS stride (shorts) for h1/h2

typedef __attribute__((ext_vector_type(8))) short bf16x8;
typedef __attribute__((ext_vector_type(4))) short bf16x4;
typedef __attribute__((ext_vector_type(4))) float f32x4;

__device__ __forceinline__ unsigned short f2bf(float x) {
    unsigned u = __float_as_uint(x);
    u += 0x7FFFu + ((u >> 16) & 1u);
    return (unsigned short)(u >> 16);
}

// pack two f32 -> two bf16 in one u32 (RNE), single HW op
__device__ __forceinline__ unsigned cvt_pk_bf16(float lo, float hi) {
    unsigned r;
    asm("v_cvt_pk_bf16_f32 %0, %1, %2" : "=v"(r) : "v"(lo), "v"(hi));
    return r;
}

// tanh(x) = 1 - 2/(exp(2x)+1); exp2 saturates to inf/0 so no clamp needed.
__device__ __forceinline__ float tanh_fast(float x) {
    float e = __builtin_amdgcn_exp2f(x * 2.8853900817779268f);
    return fmaf(-2.0f, __builtin_amdgcn_rcpf(e + 1.0f), 1.0f);
}

__global__ __launch_bounds__(256, 2)
void cstr_scan_kernel(const float* __restrict__ u_g, const float* __restrict__ z0_g,
                      const float* __restrict__ W1, const float* __restrict__ b1,
                      const float* __restrict__ W2, const float* __restrict__ b2,
                      const float* __restrict__ W3, const float* __restrict__ b3,
                      float* __restrict__ out) {
    __shared__ unsigned short zbuf[2][16][ZSTR];
    __shared__ unsigned short h1s[16][HSTR];
    __shared__ unsigned short h2s[16][HSTR];
    __shared__ float ybuf[16][16][NY];   // [t&15][row][col], flushed every 16 steps

    const int tid   = threadIdx.x;
    const int wid   = tid >> 6;          // 0..3
    const int lane  = tid & 63;
    const int b0    = blockIdx.x * 16;   // batch row base
    const int col   = lane & 15;         // MFMA col / A row
    const int kg    = lane >> 4;         // 0..3 (k-group)
    const int wrow0 = kg * 4;            // C-frag row base
    const int urow  = lane >> 2;         // u/z-shift row
    const int uc    = lane & 3;
    const int nbase = wid * 32;          // this wave's hidden-col base (2 n-tiles)

    // ---- preload weight B-fragments for this wave's 32 hidden cols ----
    bf16x8 w1f[2][2], w2f[4][2], w3f[4];
    float b1v[2], b2v[2], b3v;
#pragma unroll
    for (int nl = 0; nl < 2; ++nl) {
        b1v[nl] = b1[nbase + nl * 16 + col];
        b2v[nl] = b2[nbase + nl * 16 + col];
    }
    b3v = (col < NY) ? b3[col] : 0.f;

#pragma unroll
    for (int kc = 0; kc < 2; ++kc)
#pragma unroll
        for (int nl = 0; nl < 2; ++nl) {
            bf16x8 v;
#pragma unroll
            for (int j = 0; j < 8; ++j) {
                int k = kc * 32 + kg * 8 + j;
                float w = (k < NZV) ? W1[k * H + nbase + nl * 16 + col] : 0.f;
                v[j] = (short)f2bf(w);
            }
            w1f[kc][nl] = v;
        }
#pragma unroll
    for (int kc = 0; kc < 4; ++kc)
#pragma unroll
        for (int nl = 0; nl < 2; ++nl) {
            bf16x8 v;
#pragma unroll
            for (int j = 0; j < 8; ++j) {
                int k = kc * 32 + kg * 8 + j;
                v[j] = (short)f2bf(W2[k * H + nbase + nl * 16 + col]);
            }
            w2f[kc][nl] = v;
        }
#pragma unroll
    for (int kc = 0; kc < 4; ++kc) {
        bf16x8 v;
#pragma unroll
        for (int j = 0; j < 8; ++j) {
            int k = kc * 32 + kg * 8 + j;
            float w = (col < NY) ? W3[k * NY + col] : 0.f;
            v[j] = (short)f2bf(w);
        }
        w3f[kc] = v;
    }

    // ---- init z state (bf16) ----
    {
        unsigned short* zs = &zbuf[0][0][0];
        for (int i = tid; i < 2 * 16 * ZSTR; i += 256) zs[i] = 0;
        __syncthreads();
        for (int i = tid; i < 16 * NZV; i += 256) {
            int r = i / NZV, c = i - r * NZV;
            zbuf[0][r][c] = f2bf(z0_g[(size_t)(b0 + r) * NZV + c]);
        }
        __syncthreads();
    }

    // u running pointer (wave 3 only uses it)
    const float* uptr = u_g + (size_t)(b0 + urow) * (T_STEPS * NU) + uc;
    float ureg = 0.f, ureg_n = 0.f;
    if (wid == 3) ureg = *uptr;

    int t = 0;

    // ---- one recurrence step; CUR is a compile-time 0/1 ----
#define STEP_BODY(CUR)                                                                  \
    {                                                                                   \
        const int nxt = (CUR) ^ 1;                                                      \
        /* phase 1: GEMM1 (z @ W1) on this wave's 32 cols */                            \
        bf16x8 za0 = *(const bf16x8*)&zbuf[CUR][col][kg * 8];                           \
        bf16x8 za1 = *(const bf16x8*)&zbuf[CUR][col][32 + kg * 8];                      \
        _Pragma("unroll")                                                               \
        for (int nl = 0; nl < 2; ++nl) {                                                \
            f32x4 c1 = { b1v[nl], b1v[nl], b1v[nl], b1v[nl] };                          \
            c1 = __builtin_amdgcn_mfma_f32_16x16x32_bf16(za0, w1f[0][nl], c1, 0, 0, 0); \
            c1 = __builtin_amdgcn_mfma_f32_16x16x32_bf16(za1, w1f[1][nl], c1, 0, 0, 0); \
            unsigned p01 = cvt_pk_bf16(tanh_fast(c1[0]), tanh_fast(c1[1]));             \
            unsigned p23 = cvt_pk_bf16(tanh_fast(c1[2]), tanh_fast(c1[3]));             \
            const int n = nbase + nl * 16 + col;                                        \
            h1s[wrow0 + 0][n] = (unsigned short)p01;                                    \
            h1s[wrow0 + 1][n] = (unsigned short)(p01 >> 16);                            \
            h1s[wrow0 + 2][n] = (unsigned short)p23;                                    \
            h1s[wrow0 + 3][n] = (unsigned short)(p23 >> 16);                            \
        }                                                                               \
        /* wave3: z shift CUR->nxt + u insert (y slot untouched) + u prefetch */        \
        if (wid == 3) {                                                                 \
            bf16x4 m0 = *(const bf16x4*)&zbuf[CUR][urow][8 + 8 * uc];                   \
            bf16x4 m1 = *(const bf16x4*)&zbuf[CUR][urow][12 + 8 * uc];                  \
            bf16x4 m2 = *(const bf16x4*)&zbuf[CUR][urow][44 + 4 * uc];                  \
            *(bf16x4*)&zbuf[nxt][urow][8 * uc]      = m0;                               \
            *(bf16x4*)&zbuf[nxt][urow][8 * uc + 4]  = m1;                               \
            *(bf16x4*)&zbuf[nxt][urow][40 + 4 * uc] = m2;                               \
            zbuf[nxt][urow][56 + uc] = f2bf(ureg);                                      \
            uptr += NU;                                                                 \
            if (t + 1 < T_STEPS) ureg_n = *uptr;                                        \
        }                                                                               \
        __syncthreads();   /* B1: h1 ready; z[nxt] (minus y) ready */                   \
        /* phase 2: GEMM2 (h1 @ W2, full K=128) */                                      \
        bf16x8 ha0 = *(const bf16x8*)&h1s[col][0 * 32 + kg * 8];                        \
        bf16x8 ha1 = *(const bf16x8*)&h1s[col][1 * 32 + kg * 8];                        \
        bf16x8 ha2 = *(const bf16x8*)&h1s[col][2 * 32 + kg * 8];                        \
        bf16x8 ha3 = *(const bf16x8*)&h1s[col][3 * 32 + kg * 8];                        \
        _Pragma("unroll")                                                               \
        for (int nl = 0; nl < 2; ++nl) {                                                \
            f32x4 a0 = { b2v[nl], b2v[nl], b2v[nl], b2v[nl] };                          \
            f32x4 a1 = { 0.f, 0.f, 0.f, 0.f };                                          \
            a0 = __builtin_amdgcn_mfma_f32_16x16x32_bf16(ha0, w2f[0][nl], a0, 0, 0, 0); \
            a1 = __builtin_amdgcn_mfma_f32_16x16x32_bf16(ha1, w2f[1][nl], a1, 0, 0, 0); \
            a0 = __builtin_amdgcn_mfma_f32_16x16x32_bf16(ha2, w2f[2][nl], a0, 0, 0, 0); \
            a1 = __builtin_amdgcn_mfma_f32_16x16x32_bf16(ha3, w2f[3][nl], a1, 0, 0, 0); \
            f32x4 c2 = a0 + a1;                                                         \
            unsigned p01 = cvt_pk_bf16(tanh_fast(c2[0]), tanh_fast(c2[1]));             \
            unsigned p23 = cvt_pk_bf16(tanh_fast(c2[2]), tanh_fast(c2[3]));             \
            const int n = nbase + nl * 16 + col;                                        \
            h2s[wrow0 + 0][n] = (unsigned short)p01;                                    \
            h2s[wrow0 + 1][n] = (unsigned short)(p01 >> 16);                            \
            h2s[wrow0 + 2][n] = (unsigned short)p23;                                    \
            h2s[wrow0 + 3][n] = (unsigned short)(p23 >> 16);                            \
        }                                                                               \
        __syncthreads();   /* B2: h2 ready */                                           \
        /* phase 3: wave0 only — GEMM3, y -> z[nxt] slot + ybuf */                      \
        if (wid == 0) {                                                                 \
            bf16x8 hp0 = *(const bf16x8*)&h2s[col][0 * 32 + kg * 8];                    \
            bf16x8 hp1 = *(const bf16x8*)&h2s[col][1 * 32 + kg * 8];                    \
            bf16x8 hp2 = *(const bf16x8*)&h2s[col][2 * 32 + kg * 8];                    \
            bf16x8 hp3 = *(const bf16x8*)&h2s[col][3 * 32 + kg * 8];                    \
            f32x4 ya = { b3v, b3v, b3v, b3v };                                          \
            f32x4 yb = { 0.f, 0.f, 0.f, 0.f };                                          \
            ya = __builtin_amdgcn_mfma_f32_16x16x32_bf16(hp0, w3f[0], ya, 0, 0, 0);     \
            yb = __builtin_amdgcn_mfma_f32_16x16x32_bf16(hp1, w3f[1], yb, 0, 0, 0);     \
            ya = __builtin_amdgcn_mfma_f32_16x16x32_bf16(hp2, w3f[2], ya, 0, 0, 0);     \
            yb = __builtin_amdgcn_mfma_f32_16x16x32_bf16(hp3, w3f[3], yb, 0, 0, 0);     \
            f32x4 y = ya + yb;                                                          \
            if (col < NY) {                                                             \
                unsigned q01 = cvt_pk_bf16(y[0], y[1]);                                 \
                unsigned q23 = cvt_pk_bf16(y[2], y[3]);                                 \
                zbuf[nxt][wrow0 + 0][32 + col] = (unsigned short)q01;                   \
                zbuf[nxt][wrow0 + 1][32 + col] = (unsigned short)(q01 >> 16);           \
                zbuf[nxt][wrow0 + 2][32 + col] = (unsigned short)q23;                   \
                zbuf[nxt][wrow0 + 3][32 + col] = (unsigned short)(q23 >> 16);           \
                const int ts = t & 15;                                                  \
                ybuf[ts][wrow0 + 0][col] = y[0];                                        \
                ybuf[ts][wrow0 + 1][col] = y[1];                                        \
                ybuf[ts][wrow0 + 2][col] = y[2];                                        \
                ybuf[ts][wrow0 + 3][col] = y[3];                                        \
            }                                                                           \
        }                                                                               \
        __syncthreads();   /* B3: z[nxt] fully valid; ybuf slot committed */            \
        ureg = ureg_n;                                                                  \
        ++t;                                                                            \
    }

    // coalesced ybuf flush: 16 steps x 16 rows x 8 f32; thread -> one (row,toff) pair
    const int frow  = tid >> 4;    // 0..15
    const int ftoff = tid & 15;    // 0..15

#define FLUSH(BASE_T)                                                                   \
    {                                                                                   \
        const f32x4* yp = (const f32x4*)&ybuf[ftoff][frow][0];                          \
        f32x4 v0 = yp[0], v1 = yp[1];                                                   \
        float* op = out + ((size_t)(b0 + frow) * T_STEPS + (BASE_T) + ftoff) * NY;      \
        *(f32x4*)op = v0;                                                               \
        *(f32x4*)(op + 4) = v1;                                                         \
    }

#pragma unroll 1
    for (int it = 0; it < T_STEPS / 2; ++it) {
        if ((t & 15) == 0 && t > 0)
            FLUSH(t - 16);       // reads drain at B1; slot rewrites happen after B2
        STEP_BODY(0)
        STEP_BODY(1)
    }
    // final window
    FLUSH(T_STEPS - 16);
#undef STEP_BODY
#undef FLUSH
}

extern "C" void kernel_launch(void* const* d_in, const int* in_sizes, int n_in,
                              void* d_out, int out_size, void* d_ws, size_t ws_size,
                              hipStream_t stream) {
    (void)in_sizes; (void)n_in; (void)d_ws; (void)ws_size; (void)out_size;
    const float* u  = (const float*)d_in[0];
    const float* z0 = (const float*)d_in[1];
    const float* W1 = (const float*)d_in[2];
    const float* b1 = (const float*)d_in[3];
    const float* W2 = (const float*)d_in[4];
    const float* b2 = (const float*)d_in[5];
    const float* W3 = (const float*)d_in[6];
    const float* b3 = (const float*)d_in[7];
    float* out = (float*)d_out;

    dim3 grid(8192 / 16);   // 512 blocks x 4 waves; 16 batch rows/block
    dim3 block(256);
    cstr_scan_kernel<<<grid, block, 0, stream>>>(u, z0, W1, b1, W2, b2, W3, b3, out);
}